// Round 9
// baseline (371.593 us; speedup 1.0000x reference)
//
#include <hip/hip_runtime.h>
#include <hip/hip_cooperative_groups.h>

namespace cg = cooperative_groups;

// ---------------------------------------------------------------------------
// HiPPO-LegT via scalar-kernel convolution, 2 launches:
//   pred[b][t] = fac_t * sum_{s<=t} k[t-s] x[b][s] + D x[b][t],  k[tau]=C A^tau B
// Launch 1 (cooperative genk, 256 blk x 512 thr, __launch_bounds__(512,1):
//   1 block/CU -> VGPR cap >= 256 so areg[128]/mreg[128] stay in registers):
//   xsplit+P2 | P4 | P8 | P16 | P32 | P64T | P128T || W-chains(4x16) |
//   P256T || V-starts | V-chains(4x16, step A^256) | kfrag (K dots + A-frags,
//   159-wide kl window: fragment m needs k[16m-31 .. 16m+127])
// Launch 2: convm — round-4 MFMA Toeplitz GEMM (8-wave k-split, LDS reduce,
//   coalesced exclusive stores).
// Fallback if coop launch fails: genk replayed per-phase (stream-ordered).
// ---------------------------------------------------------------------------

#define LENGTH 4096

// ws layout (float offsets)
#define WS_P2    0
#define WS_P4    65536
#define WS_P8    131072
#define WS_P16   196608
#define WS_P32   262144
#define WS_P64T  327680
#define WS_P128T 393216
#define WS_P256T 458752
#define WS_W     524288   // 64 x 256
#define WS_V     540672   // 64 x 256
#define WS_XH    557056   // 1M shorts = 524288 floats
#define WS_XL    1081344
#define WS_AH    1605632  // 256*64*8 shorts = 65536 floats
#define WS_AL    1671168

typedef __attribute__((ext_vector_type(8))) short bf16x8;
typedef __attribute__((ext_vector_type(4))) float f32x4;
#define MFMA(a, b, c) __builtin_amdgcn_mfma_f32_16x16x32_bf16(a, b, c, 0, 0, 0)

__device__ inline unsigned short f2bf(float f) {
    unsigned int u = __float_as_uint(f);
    return (unsigned short)((u + 0x7FFFu + ((u >> 16) & 1u)) >> 16);
}
__device__ inline void split2(float f, short& h, short& l) {
    unsigned short hu = f2bf(f);
    float fh = __uint_as_float((unsigned int)hu << 16);
    h = (short)hu;
    l = (short)f2bf(f - fh);
}

// ---- 256x256 row-matmul: Z(row) = X(row)*Y; 512 thr, k-split 2 ----
__device__ __forceinline__ void mm_body(const float* __restrict__ X,
                                        const float* __restrict__ Y,
                                        float* __restrict__ Z,
                                        int row, int t, bool trans, float* red) {
    const int j = t & 255, p = t >> 8;          // p in {0,1}
    const float* xr = X + row * 256 + 128 * p;
    const float* yc = Y + (128 * p) * 256 + j;
    float a0 = 0.f, a1 = 0.f, a2 = 0.f, a3 = 0.f;
#pragma unroll
    for (int l = 0; l < 128; l += 4) {
        a0 = fmaf(xr[l + 0], yc[(l + 0) * 256], a0);
        a1 = fmaf(xr[l + 1], yc[(l + 1) * 256], a1);
        a2 = fmaf(xr[l + 2], yc[(l + 2) * 256], a2);
        a3 = fmaf(xr[l + 3], yc[(l + 3) * 256], a3);
    }
    float s = (a0 + a1) + (a2 + a3);
    __syncthreads();              // guard red reuse across back-to-back calls
    if (p) red[j] = s;
    __syncthreads();
    if (!p) {
        float z = s + red[j];
        if (trans) Z[j * 256 + row] = z;
        else       Z[row * 256 + j] = z;
    }
}

// curl[j] = sum_i v[i] * M[i*256+j]   (row-vector x matrix), k-split 2
__device__ __forceinline__ void rv_mm(const float* __restrict__ v,
                                      const float* __restrict__ M,
                                      float* curl, float* red2, int j, int p) {
    float s0 = 0.f, s1 = 0.f;
#pragma unroll
    for (int ii = 0; ii < 128; ii += 2) {
        s0 = fmaf(v[128 * p + ii],     M[(128 * p + ii) * 256 + j],     s0);
        s1 = fmaf(v[128 * p + ii + 1], M[(128 * p + ii + 1) * 256 + j], s1);
    }
    red2[p * 256 + j] = s0 + s1;
    __syncthreads();
    if (!p) curl[j] = red2[j] + red2[256 + j];
    __syncthreads();
}

// curl[i] = sum_j MT[j*256+i] * v[j]   (T-stored matrix x col-vector)
__device__ __forceinline__ void cv_mm(const float* __restrict__ MT,
                                      const float* __restrict__ v,
                                      float* curl, float* red2, int i, int p) {
    float s0 = 0.f, s1 = 0.f;
#pragma unroll
    for (int jj = 0; jj < 128; jj += 2) {
        s0 = fmaf(MT[(128 * p + jj) * 256 + i],     v[128 * p + jj],     s0);
        s1 = fmaf(MT[(128 * p + jj + 1) * 256 + i], v[128 * p + jj + 1], s1);
    }
    red2[p * 256 + i] = s0 + s1;
    __syncthreads();
    if (!p) curl[i] = red2[i] + red2[256 + i];
    __syncthreads();
}

// ===========================================================================
// genk: generation pipeline. ph < 0: cooperative (all phases + grid.sync);
// ph = 0..9: run only that phase (fallback, stream-ordered launches).
// __launch_bounds__(512, 1): 1 block/CU -> VGPR cap >= 256 (no spill).
// ===========================================================================
__global__ __launch_bounds__(512, 1) void genk(const float* __restrict__ x,
                                               const float* __restrict__ A,
                                               const float* __restrict__ B,
                                               const float* __restrict__ C,
                                               float* __restrict__ ws,
                                               int ph) {
    const bool coop = (ph < 0);
    cg::grid_group grid = cg::this_grid();
    const int bid = blockIdx.x;
    const int t = threadIdx.x;
    const int j = t & 255, p = t >> 8;          // p in {0,1}

    // 17377 floats = 69.5 KB: kfrag needs Wl(64*257)+Vl(768)+kl(160)
    __shared__ __align__(16) float shm[17377];
    float* red  = shm;          // 256 (mm_body scratch)
    float* curl = shm + 1024;   // 256
    float* red2 = shm + 1280;   // 512

    float* P2    = ws + WS_P2;
    float* P4    = ws + WS_P4;
    float* P8    = ws + WS_P8;
    float* P16   = ws + WS_P16;
    float* P32   = ws + WS_P32;
    float* P64T  = ws + WS_P64T;
    float* P128T = ws + WS_P128T;
    float* P256T = ws + WS_P256T;
    float* Wm    = ws + WS_W;
    float* Vm    = ws + WS_V;
    short* XH    = (short*)(ws + WS_XH);
    short* XL    = (short*)(ws + WS_XL);
    short* AH    = (short*)(ws + WS_AH);
    short* AL    = (short*)(ws + WS_AL);

    // ---- ph0: P2 = A*A  +  xsplit (8 wave-jobs per block) ----
    if (coop || ph == 0) {
        mm_body(A, A, P2, bid, t, false, red);
        const int wv = t >> 6, lane = t & 63;
        const int pj = bid * 8 + wv;                 // 0..2047
        const int c = pj >> 4, blk = pj & 15;
        const int b = blk * 16 + (lane & 15);
        const int s0 = c * 32 + 8 * (lane >> 4);
        const float4 v0 = reinterpret_cast<const float4*>(&x[b * LENGTH + s0])[0];
        const float4 v1 = reinterpret_cast<const float4*>(&x[b * LENGTH + s0])[1];
        const float f[8] = {v0.x, v0.y, v0.z, v0.w, v1.x, v1.y, v1.z, v1.w};
        bf16x8 hv, lv;
#pragma unroll
        for (int e = 0; e < 8; ++e) {
            short h_, l_;
            split2(f[e], h_, l_);
            hv[e] = h_; lv[e] = l_;
        }
        const int off = (pj * 64 + lane) * 8;
        *reinterpret_cast<bf16x8*>(XH + off) = hv;
        *reinterpret_cast<bf16x8*>(XL + off) = lv;
    }
    if (coop) grid.sync();
    if (coop || ph == 1) mm_body(P2, P2, P4, bid, t, false, red);
    if (coop) grid.sync();
    if (coop || ph == 2) mm_body(P4, P4, P8, bid, t, false, red);
    if (coop) grid.sync();
    if (coop || ph == 3) mm_body(P8, P8, P16, bid, t, false, red);
    if (coop) grid.sync();
    if (coop || ph == 4) mm_body(P16, P16, P32, bid, t, false, red);
    if (coop) grid.sync();
    if (coop || ph == 5) mm_body(P32, P32, P64T, bid, t, true, red);
    if (coop) grid.sync();

    // ---- ph6: P128T = P64T^2 (blocks 4..255) || W chains 4x16 (blocks 0..3)
    if (coop || ph == 6) {
        if (bid >= 4) {
            mm_body(P64T, P64T, P128T, bid - 4, t, false, red);
            if (bid < 8) mm_body(P64T, P64T, P128T, 248 + bid, t, false, red);
        } else {
            const int c = bid;                   // W[16c+s] = C A^{16c} A^s
            float areg[128];
#pragma unroll
            for (int ii = 0; ii < 128; ++ii) areg[ii] = A[(128 * p + ii) * 256 + j];
            if (c == 0) {
                if (t < 256) curl[t] = C[t];
                __syncthreads();
            } else {
                rv_mm(C, (c == 2) ? P32 : P16, curl, red2, j, p);
                if (c == 3) rv_mm(curl, P32, curl, red2, j, p);
            }
            for (int s_ = 0; s_ < 16; ++s_) {
                if (!p) Wm[(16 * c + s_) * 256 + j] = curl[j];
                if (s_ == 15) break;
                float s0 = 0.f, s1 = 0.f;
#pragma unroll
                for (int m = 0; m < 32; ++m) {
                    float4 c4 = *reinterpret_cast<const float4*>(&curl[128 * p + 4 * m]);
                    s0 = fmaf(c4.x, areg[4 * m + 0], s0);
                    s1 = fmaf(c4.y, areg[4 * m + 1], s1);
                    s0 = fmaf(c4.z, areg[4 * m + 2], s0);
                    s1 = fmaf(c4.w, areg[4 * m + 3], s1);
                }
                red2[p * 256 + j] = s0 + s1;
                __syncthreads();
                if (!p) curl[j] = red2[j] + red2[256 + j];
                __syncthreads();
            }
        }
    }
    if (coop) grid.sync();

    // ---- ph7: P256T = P128T^2 (blocks 4..255) || V starts -> Vm[0..3] ----
    if (coop || ph == 7) {
        if (bid >= 4) {
            mm_body(P128T, P128T, P256T, bid - 4, t, false, red);
            if (bid < 8) mm_body(P128T, P128T, P256T, 248 + bid, t, false, red);
        } else {
            const int c = bid;                   // V[c] = A^{64c} B
            if (c == 0) {
                if (t < 256) Vm[t] = B[t];
            } else if (c == 1) {
                cv_mm(P64T, B, curl, red2, j, p);
                if (!p) Vm[256 + j] = curl[j];
            } else if (c == 2) {
                cv_mm(P128T, B, curl, red2, j, p);
                if (!p) Vm[512 + j] = curl[j];
            } else {
                cv_mm(P128T, B, curl, red2, j, p);
                cv_mm(P64T, curl, curl, red2, j, p);
                if (!p) Vm[768 + j] = curl[j];
            }
        }
    }
    if (coop) grid.sync();

    // ---- ph8: V chains (blocks 0..3): V[4s+c] = (A^256)^s V[c] ----
    if (coop || ph == 8) {
        if (bid < 4) {
            const int c = bid, i = j;
            if (t < 256) curl[t] = Vm[c * 256 + t];
            __syncthreads();
            float mreg[128];
#pragma unroll
            for (int jj = 0; jj < 128; ++jj) mreg[jj] = P256T[(128 * p + jj) * 256 + i];
            for (int s_ = 1; s_ < 16; ++s_) {
                float s0 = 0.f, s1 = 0.f;
#pragma unroll
                for (int m = 0; m < 32; ++m) {
                    float4 c4 = *reinterpret_cast<const float4*>(&curl[128 * p + 4 * m]);
                    s0 = fmaf(c4.x, mreg[4 * m + 0], s0);
                    s1 = fmaf(c4.y, mreg[4 * m + 1], s1);
                    s0 = fmaf(c4.z, mreg[4 * m + 2], s0);
                    s1 = fmaf(c4.w, mreg[4 * m + 3], s1);
                }
                red2[p * 256 + i] = s0 + s1;
                __syncthreads();
                if (!p) {
                    float s = red2[i] + red2[256 + i];
                    curl[i] = s;
                    Vm[(4 * s_ + c) * 256 + i] = s;
                }
                __syncthreads();
            }
        }
    }
    if (coop) grid.sync();

    // ---- ph9: kfrag (blocks 0..31): K dots + Toeplitz A-fragments ----
    // fragment m needs k[16m-31 .. 16m+127] -> kl window 159 wide
    if (coop || ph == 9) {
        if (bid < 32) {
            float* Wl = shm;             // 64 x 257
            float* Vl = shm + 16448;     // 3 x 256
            float* kl = shm + 17216;     // 159 (+pad)
            for (int u = t; u < 16384; u += 512)
                Wl[(u >> 8) * 257 + (u & 255)] = Wm[u];
            for (int u = t; u < 768; u += 512) {
                const int q = 2 * bid - 1 + (u >> 8);
                Vl[u] = (q >= 0) ? Vm[q * 256 + (u & 255)] : 0.f;
            }
            __syncthreads();
            if (t < 159) {
                const int tau = 128 * bid - 31 + t;
                float s = 0.f;
                if (tau >= 0) {
                    const int r = tau & 63;
                    const int qq = (tau >> 6) - (2 * bid - 1);
                    const float* wr = &Wl[r * 257];
                    const float* vr = &Vl[qq * 256];
                    float s0 = 0.f, s1 = 0.f, s2 = 0.f, s3 = 0.f;
#pragma unroll 8
                    for (int i2 = 0; i2 < 256; i2 += 4) {
                        s0 = fmaf(wr[i2 + 0], vr[i2 + 0], s0);
                        s1 = fmaf(wr[i2 + 1], vr[i2 + 1], s1);
                        s2 = fmaf(wr[i2 + 2], vr[i2 + 2], s2);
                        s3 = fmaf(wr[i2 + 3], vr[i2 + 3], s3);
                    }
                    s = (s0 + s1) + (s2 + s3);
                }
                kl[t] = s;
            }
            __syncthreads();
            const int wv = t >> 6, lane = t & 63;
            const int m = 8 * bid + wv;
            bf16x8 hv, lv;
#pragma unroll
            for (int el = 0; el < 8; ++el) {
                const int rel = 16 * wv + (lane & 15) - 8 * (lane >> 4) - el + 31;
                short h_, l_;
                split2(kl[rel], h_, l_);          // rel always in [0,158]
                hv[el] = h_; lv[el] = l_;
            }
            const int off = (m * 64 + lane) * 8;
            *reinterpret_cast<bf16x8*>(AH + off) = hv;
            *reinterpret_cast<bf16x8*>(AL + off) = lv;
        }
    }
}

// ===========================================================================
// convm — round-4 version (known good): 256 blocks = 32 pairs x 8 btiles(32b);
// 8 waves k-split the pair's 130 chunks (strided); double-buffered fragments;
// LDS reduce; coalesced exclusive float4 stores.
// ===========================================================================
struct Frag {
    bf16x8 bh0, bh1, bl0, bl1;
    bf16x8 ah0, ah1, ah2, ah3, al0, al1, al2, al3;
    int d0, tile;
};

#define LOADF(F, IDX_) do {                                                    \
        const int i_ = (IDX_);                                                 \
        const int tl_ = (i_ < nA) ? 0 : 1;                                     \
        const int cc_ = i_ - (tl_ ? nA : 0);                                   \
        const int xo_ = ((cc_ * 16 + bt2) * 64 + lane) * 8;                    \
        F.bh0 = *reinterpret_cast<const bf16x8*>(XH + xo_);                    \
        F.bh1 = *reinterpret_cast<const bf16x8*>(XH + xo_ + 512);              \
        F.bl0 = *reinterpret_cast<const bf16x8*>(XL + xo_);                    \
        F.bl1 = *reinterpret_cast<const bf16x8*>(XL + xo_ + 512);              \
        const int d_ = (tl_ ? tB64 : tA64) - cc_ * 32;                         \
        F.d0 = d_; F.tile = tl_;                                               \
        const int m0_ = (d_ > 0 ? d_ : 0) >> 4;                                \
        const int m1_ = (d_ + 16 > 0 ? d_ + 16 : 0) >> 4;                      \
        const int m2_ = (d_ + 32 > 0 ? d_ + 32 : 0) >> 4;                      \
        const int m3_ = (d_ + 48 > 0 ? d_ + 48 : 0) >> 4;                      \
        F.ah0 = *reinterpret_cast<const bf16x8*>(AH + (m0_ * 64 + lane) * 8);  \
        F.al0 = *reinterpret_cast<const bf16x8*>(AL + (m0_ * 64 + lane) * 8);  \
        F.ah1 = *reinterpret_cast<const bf16x8*>(AH + (m1_ * 64 + lane) * 8);  \
        F.al1 = *reinterpret_cast<const bf16x8*>(AL + (m1_ * 64 + lane) * 8);  \
        F.ah2 = *reinterpret_cast<const bf16x8*>(AH + (m2_ * 64 + lane) * 8);  \
        F.al2 = *reinterpret_cast<const bf16x8*>(AL + (m2_ * 64 + lane) * 8);  \
        F.ah3 = *reinterpret_cast<const bf16x8*>(AH + (m3_ * 64 + lane) * 8);  \
        F.al3 = *reinterpret_cast<const bf16x8*>(AL + (m3_ * 64 + lane) * 8);  \
    } while (0)

#define ONER(F, T, R, AHF, ALF)                                                \
        if (F.d0 + 16 * R >= 0) {                                              \
            acc[T][R][0] = MFMA(F.AHF, F.bh0, acc[T][R][0]);                   \
            acc[T][R][1] = MFMA(F.AHF, F.bh1, acc[T][R][1]);                   \
            acc[T][R][0] = MFMA(F.AHF, F.bl0, acc[T][R][0]);                   \
            acc[T][R][1] = MFMA(F.AHF, F.bl1, acc[T][R][1]);                   \
            acc[T][R][0] = MFMA(F.ALF, F.bh0, acc[T][R][0]);                   \
            acc[T][R][1] = MFMA(F.ALF, F.bh1, acc[T][R][1]);                   \
        }

#define APPLY(F) do {                                                          \
        if (F.tile == 0) {                                                     \
            ONER(F, 0, 0, ah0, al0) ONER(F, 0, 1, ah1, al1)                    \
            ONER(F, 0, 2, ah2, al2) ONER(F, 0, 3, ah3, al3)                    \
        } else {                                                               \
            ONER(F, 1, 0, ah0, al0) ONER(F, 1, 1, ah1, al1)                    \
            ONER(F, 1, 2, ah2, al2) ONER(F, 1, 3, ah3, al3)                    \
        }                                                                      \
    } while (0)

__global__ __launch_bounds__(512) void convm(const short* __restrict__ XH,
                                             const short* __restrict__ XL,
                                             const short* __restrict__ AH,
                                             const short* __restrict__ AL,
                                             const float* __restrict__ x,
                                             const float* __restrict__ Dp,
                                             float* __restrict__ out) {
    const int pr = blockIdx.x & 31;
    const int bt = blockIdx.x >> 5;
    const int tid = threadIdx.x;
    const int w = tid >> 6, lane = tid & 63;
    const int tA64 = pr * 64, tB64 = (63 - pr) * 64;
    const int nA = 2 * pr + 2;
    const int bt2 = bt * 2;

    __shared__ float lds[16 * 64 * 34];

    f32x4 acc[2][4][2];
#pragma unroll
    for (int t_ = 0; t_ < 2; ++t_)
#pragma unroll
        for (int r_ = 0; r_ < 4; ++r_)
#pragma unroll
            for (int c_ = 0; c_ < 2; ++c_) acc[t_][r_][c_] = f32x4{0.f, 0.f, 0.f, 0.f};

    Frag f0, f1;
    LOADF(f0, w);
    int idx = w;
    while (true) {
        const int n1 = idx + 8;
        const bool h1 = n1 < 130;
        if (h1) LOADF(f1, n1);
        APPLY(f0);
        if (!h1) break;
        const int n2 = n1 + 8;
        const bool h2 = n2 < 130;
        if (h2) LOADF(f0, n2);
        APPLY(f1);
        if (!h2) break;
        idx = n2;
    }

    const int lq = lane >> 4, lr = lane & 15;
#pragma unroll
    for (int t_ = 0; t_ < 2; ++t_)
#pragma unroll
        for (int r_ = 0; r_ < 4; ++r_)
#pragma unroll
            for (int c_ = 0; c_ < 2; ++c_)
#pragma unroll
                for (int e_ = 0; e_ < 4; ++e_)
                    lds[((w * 2 + t_) * 64 + (r_ * 16 + lq * 4 + e_)) * 34 +
                        (c_ * 16 + lr)] = acc[t_][r_][c_][e_];
    __syncthreads();

    const float D = Dp[0];
    const int b = tid >> 4;
    const int t4 = (tid & 15) * 4;
#pragma unroll
    for (int t_ = 0; t_ < 2; ++t_) {
        const int tbase = t_ ? tB64 : tA64;
        float s0 = 0.f, s1 = 0.f, s2 = 0.f, s3 = 0.f;
#pragma unroll
        for (int w_ = 0; w_ < 8; ++w_) {
            const float* lp = &lds[((w_ * 2 + t_) * 64 + t4) * 34 + b];
            s0 += lp[0]; s1 += lp[34]; s2 += lp[68]; s3 += lp[102];
        }
        const int g = (bt * 32 + b) * LENGTH + tbase + t4;
        const float4 xv = *reinterpret_cast<const float4*>(x + g);
        float4 o;
        o.x = 2.f * s0 + D * xv.x;
        o.y = 2.f * s1 + D * xv.y;
        o.z = 2.f * s2 + D * xv.z;
        o.w = 2.f * s3 + D * xv.w;
        if (tbase == 0 && t4 == 0) o.x -= s0;     // t==0: fac is 1, not 2
        *reinterpret_cast<float4*>(out + g) = o;
    }
}

extern "C" void kernel_launch(void* const* d_in, const int* in_sizes, int n_in,
                              void* d_out, int out_size, void* d_ws, size_t ws_size,
                              hipStream_t stream) {
    const float* x  = (const float*)d_in[0];
    const float* A  = (const float*)d_in[1];
    const float* B  = (const float*)d_in[2];
    const float* C  = (const float*)d_in[3];
    const float* Dp = (const float*)d_in[4];
    float* out = (float*)d_out;
    float* ws  = (float*)d_ws;

    short* XHs = (short*)(ws + WS_XH);
    short* XLs = (short*)(ws + WS_XL);
    short* AHs = (short*)(ws + WS_AH);
    short* ALs = (short*)(ws + WS_AL);

    int ph = -1;
    void* args[] = {(void*)&x, (void*)&A, (void*)&B, (void*)&C, (void*)&ws, (void*)&ph};
    hipError_t e = hipLaunchCooperativeKernel((const void*)genk, dim3(256), dim3(512),
                                              args, 0, stream);
    if (e != hipSuccess) {
        // fallback: same kernel, one phase per launch (stream provides ordering)
        for (int i = 0; i <= 9; ++i)
            genk<<<256, 512, 0, stream>>>(x, A, B, C, ws, i);
    }
    convm<<<256, 512, 0, stream>>>(XHs, XLs, AHs, ALs, x, Dp, out);
}

// Round 10
// 120.476 us; speedup vs baseline: 3.0844x; 3.0844x over previous
//
#include <hip/hip_runtime.h>

// ---------------------------------------------------------------------------
// HiPPO-LegT via scalar-kernel convolution (10-launch pipeline, no coop):
//   pred[b][t] = fac_t * sum_{s<=t} k[t-s] x[b][s] + D x[b][t],  k[tau]=C A^tau B
// k factorized: k[64q+r] = (C A^r) . (A^{64q} B) = W[r] . V[q]
//   W: 4 chains x 16 steps stepping A (starts C, C P16, C P32, C P16 P32),
//      fused into the P64T launch (blocks 0..3).
//   V: 2 chains x 32 steps stepping A^128 (starts B, P64T B).
// kfrag: fused K dots + Toeplitz MFMA A-fragment build (validated r8/r9).
// convm: round-4 MFMA Toeplitz GEMM (validated r4/r7/r8/r9).
// All chain kernels: 1024 thr, areg[64] (k-split 4) -> ~96 VGPR, no spill.
// ---------------------------------------------------------------------------

#define LENGTH 4096

// ws layout (float offsets)
#define WS_P2    0
#define WS_P4    65536
#define WS_P8    131072
#define WS_P16   196608
#define WS_P32   262144
#define WS_P64T  327680
#define WS_P128T 393216
#define WS_W     458752   // 64 x 256
#define WS_V     475136   // 64 x 256
#define WS_XH    491520   // 1M shorts = 524288 floats
#define WS_XL    1015808
#define WS_AH    1540096  // 256*64*8 shorts = 65536 floats
#define WS_AL    1605632

typedef __attribute__((ext_vector_type(8))) short bf16x8;
typedef __attribute__((ext_vector_type(4))) float f32x4;
#define MFMA(a, b, c) __builtin_amdgcn_mfma_f32_16x16x32_bf16(a, b, c, 0, 0, 0)

__device__ inline unsigned short f2bf(float f) {
    unsigned int u = __float_as_uint(f);
    return (unsigned short)((u + 0x7FFFu + ((u >> 16) & 1u)) >> 16);
}
__device__ inline void split2(float f, short& h, short& l) {
    unsigned short hu = f2bf(f);
    float fh = __uint_as_float((unsigned int)hu << 16);
    h = (short)hu;
    l = (short)f2bf(f - fh);
}

// ---- 256x256 row-matmul body: Z(row) = X(row) * Y; 1024 thr, k-split 4 ----
__device__ __forceinline__ void mm_body(const float* __restrict__ X,
                                        const float* __restrict__ Y,
                                        float* __restrict__ Z,
                                        int row, int t, bool trans, float* red) {
    const int j = t & 255, p = t >> 8;
    const float* xr = X + row * 256 + 64 * p;
    const float* yc = Y + (64 * p) * 256 + j;
    float a0 = 0.f, a1 = 0.f, a2 = 0.f, a3 = 0.f;
#pragma unroll
    for (int l = 0; l < 64; l += 4) {
        a0 = fmaf(xr[l + 0], yc[(l + 0) * 256], a0);
        a1 = fmaf(xr[l + 1], yc[(l + 1) * 256], a1);
        a2 = fmaf(xr[l + 2], yc[(l + 2) * 256], a2);
        a3 = fmaf(xr[l + 3], yc[(l + 3) * 256], a3);
    }
    float s = (a0 + a1) + (a2 + a3);
    if (p) red[(p - 1) * 256 + j] = s;
    __syncthreads();
    if (!p) {
        float z = s + red[j] + red[256 + j] + red[512 + j];
        if (trans) Z[j * 256 + row] = z;
        else       Z[row * 256 + j] = z;
    }
}

// ---- L0: blocks 0..127: xsplit (16 wave-jobs); blocks 128..383: P2 = A*A ----
__global__ __launch_bounds__(1024) void fused0(const float* __restrict__ A,
                                               const float* __restrict__ x,
                                               float* __restrict__ P2,
                                               short* __restrict__ XH,
                                               short* __restrict__ XL) {
    __shared__ float red[3 * 256];
    const int t = threadIdx.x;
    if (blockIdx.x >= 128) {
        mm_body(A, A, P2, blockIdx.x - 128, t, false, red);
        return;
    }
    const int wv = t >> 6, lane = t & 63;
    const int pj = blockIdx.x * 16 + wv;               // 0..2047
    const int c = pj >> 4, blk = pj & 15;
    const int b = blk * 16 + (lane & 15);
    const int s0 = c * 32 + 8 * (lane >> 4);
    const float4 v0 = reinterpret_cast<const float4*>(&x[b * LENGTH + s0])[0];
    const float4 v1 = reinterpret_cast<const float4*>(&x[b * LENGTH + s0])[1];
    const float f[8] = {v0.x, v0.y, v0.z, v0.w, v1.x, v1.y, v1.z, v1.w};
    bf16x8 hv, lv;
#pragma unroll
    for (int e = 0; e < 8; ++e) {
        short h, l;
        split2(f[e], h, l);
        hv[e] = h; lv[e] = l;
    }
    const int off = (pj * 64 + lane) * 8;
    *reinterpret_cast<bf16x8*>(XH + off) = hv;
    *reinterpret_cast<bf16x8*>(XL + off) = lv;
}

// ---- generic squaring: D = S*S ----
__global__ __launch_bounds__(1024) void mmsq(const float* __restrict__ S,
                                             float* __restrict__ D) {
    __shared__ float red[3 * 256];
    mm_body(S, S, D, blockIdx.x, threadIdx.x, false, red);
}

// curl[j] = sum_i v[i] * M[i*256+j]   (row-vector x matrix), k-split 4
__device__ __forceinline__ void rv_mm(const float* __restrict__ v,
                                      const float* __restrict__ M,
                                      float* curl, float (*red4)[256],
                                      int j, int p) {
    float s0 = 0.f, s1 = 0.f;
#pragma unroll
    for (int ii = 0; ii < 64; ii += 2) {
        s0 = fmaf(v[64 * p + ii],     M[(64 * p + ii) * 256 + j],     s0);
        s1 = fmaf(v[64 * p + ii + 1], M[(64 * p + ii + 1) * 256 + j], s1);
    }
    red4[p][j] = s0 + s1;
    __syncthreads();
    if (!p) curl[j] = red4[0][j] + red4[1][j] + red4[2][j] + red4[3][j];
    __syncthreads();
}

// ---- L5: blocks 0..3: W chains 4x16; blocks 4..259: P64T = (P32*P32)^T ----
__global__ __launch_bounds__(1024) void p64w(const float* __restrict__ P32,
                                             float* __restrict__ P64T,
                                             const float* __restrict__ A,
                                             const float* __restrict__ C,
                                             const float* __restrict__ P16,
                                             float* __restrict__ W) {
    __shared__ float red[3 * 256];
    __shared__ float cur[256];
    __shared__ float red4[4][256];
    const int t = threadIdx.x;
    if (blockIdx.x >= 4) {
        mm_body(P32, P32, P64T, blockIdx.x - 4, t, true, red);
        return;
    }
    const int c = blockIdx.x;                    // chain 0..3
    const int j = t & 255, p = t >> 8;
    float areg[64];
#pragma unroll
    for (int ii = 0; ii < 64; ++ii) areg[ii] = A[(64 * p + ii) * 256 + j];

    // start = C * A^{16c}
    if (c == 0) {
        if (t < 256) cur[t] = C[t];
        __syncthreads();
    } else {
        rv_mm(C, (c == 2) ? P32 : P16, cur, red4, j, p);
        if (c == 3) rv_mm(cur, P32, cur, red4, j, p);
    }
    // 16 steps stepping A
    for (int s_ = 0; s_ < 16; ++s_) {
        if (!p) W[(16 * c + s_) * 256 + j] = cur[j];
        if (s_ == 15) break;
        float s0 = 0.f, s1 = 0.f;
#pragma unroll
        for (int m = 0; m < 16; ++m) {
            float4 c4 = *reinterpret_cast<const float4*>(&cur[64 * p + 4 * m]);
            s0 = fmaf(c4.x, areg[4 * m + 0], s0);
            s1 = fmaf(c4.y, areg[4 * m + 1], s1);
            s0 = fmaf(c4.z, areg[4 * m + 2], s0);
            s1 = fmaf(c4.w, areg[4 * m + 3], s1);
        }
        red4[p][j] = s0 + s1;
        __syncthreads();
        if (!p) cur[j] = red4[0][j] + red4[1][j] + red4[2][j] + red4[3][j];
        __syncthreads();
    }
}

// ---- L7: V chains: block c in {0,1}: V[2s+c] = (A^128)^s (A^{64c} B) ----
__global__ __launch_bounds__(1024) void vgen(const float* __restrict__ P64T,
                                             const float* __restrict__ P128T,
                                             const float* __restrict__ B,
                                             float* __restrict__ V) {
    __shared__ float cur[256];
    __shared__ float red4[4][256];
    const int t = threadIdx.x;
    const int i = t & 255, p = t >> 8;
    const int c = blockIdx.x;
    float mreg[64];
#pragma unroll
    for (int jj = 0; jj < 64; ++jj) mreg[jj] = P128T[(64 * p + jj) * 256 + i];

    if (c == 0) {
        if (t < 256) cur[t] = B[t];
        __syncthreads();
    } else {                                     // cur = A^64 B via P64T
        float s0 = 0.f, s1 = 0.f;
#pragma unroll
        for (int jj = 0; jj < 64; jj += 2) {
            s0 = fmaf(P64T[(64 * p + jj) * 256 + i],     B[64 * p + jj],     s0);
            s1 = fmaf(P64T[(64 * p + jj + 1) * 256 + i], B[64 * p + jj + 1], s1);
        }
        red4[p][i] = s0 + s1;
        __syncthreads();
        if (!p) cur[i] = red4[0][i] + red4[1][i] + red4[2][i] + red4[3][i];
        __syncthreads();
    }
    for (int s_ = 0; s_ < 32; ++s_) {
        if (!p) V[(2 * s_ + c) * 256 + i] = cur[i];
        if (s_ == 31) break;
        float s0 = 0.f, s1 = 0.f;
#pragma unroll
        for (int m = 0; m < 16; ++m) {
            float4 c4 = *reinterpret_cast<const float4*>(&cur[64 * p + 4 * m]);
            s0 = fmaf(c4.x, mreg[4 * m + 0], s0);
            s1 = fmaf(c4.y, mreg[4 * m + 1], s1);
            s0 = fmaf(c4.z, mreg[4 * m + 2], s0);
            s1 = fmaf(c4.w, mreg[4 * m + 3], s1);
        }
        red4[p][i] = s0 + s1;
        __syncthreads();
        if (!p) cur[i] = red4[0][i] + red4[1][i] + red4[2][i] + red4[3][i];
        __syncthreads();
    }
}

// ---- L8: kfrag (32 blocks x 512 thr): K dots + Toeplitz A-fragments ----
// fragment m needs k[16m-31 .. 16m+127] -> kl window 159 wide (validated r8/r9)
__global__ __launch_bounds__(512) void kfrag(const float* __restrict__ Wm,
                                             const float* __restrict__ Vm,
                                             short* __restrict__ AH,
                                             short* __restrict__ AL) {
    const int bid = blockIdx.x, t = threadIdx.x;
    __shared__ float Wl[64 * 257];
    __shared__ float Vl[768];
    __shared__ float kl[160];
    for (int u = t; u < 16384; u += 512)
        Wl[(u >> 8) * 257 + (u & 255)] = Wm[u];
    for (int u = t; u < 768; u += 512) {
        const int q = 2 * bid - 1 + (u >> 8);
        Vl[u] = (q >= 0) ? Vm[q * 256 + (u & 255)] : 0.f;
    }
    __syncthreads();
    if (t < 159) {
        const int tau = 128 * bid - 31 + t;
        float s = 0.f;
        if (tau >= 0) {
            const int r = tau & 63;
            const int qq = (tau >> 6) - (2 * bid - 1);
            const float* wr = &Wl[r * 257];
            const float* vr = &Vl[qq * 256];
            float s0 = 0.f, s1 = 0.f, s2 = 0.f, s3 = 0.f;
#pragma unroll 8
            for (int i2 = 0; i2 < 256; i2 += 4) {
                s0 = fmaf(wr[i2 + 0], vr[i2 + 0], s0);
                s1 = fmaf(wr[i2 + 1], vr[i2 + 1], s1);
                s2 = fmaf(wr[i2 + 2], vr[i2 + 2], s2);
                s3 = fmaf(wr[i2 + 3], vr[i2 + 3], s3);
            }
            s = (s0 + s1) + (s2 + s3);
        }
        kl[t] = s;
    }
    __syncthreads();
    const int wv = t >> 6, lane = t & 63;
    const int m = 8 * bid + wv;
    bf16x8 hv, lv;
#pragma unroll
    for (int el = 0; el < 8; ++el) {
        const int rel = 16 * wv + (lane & 15) - 8 * (lane >> 4) - el + 31;
        short h_, l_;
        split2(kl[rel], h_, l_);          // rel always in [0,158]
        hv[el] = h_; lv[el] = l_;
    }
    const int off = (m * 64 + lane) * 8;
    *reinterpret_cast<bf16x8*>(AH + off) = hv;
    *reinterpret_cast<bf16x8*>(AL + off) = lv;
}

// ===========================================================================
// convm — round-4 version (validated): 256 blocks = 32 pairs x 8 btiles(32b);
// 8 waves k-split the pair's 130 chunks (strided); double-buffered fragments;
// LDS reduce; coalesced exclusive float4 stores.
// ===========================================================================
struct Frag {
    bf16x8 bh0, bh1, bl0, bl1;
    bf16x8 ah0, ah1, ah2, ah3, al0, al1, al2, al3;
    int d0, tile;
};

#define LOADF(F, IDX_) do {                                                    \
        const int i_ = (IDX_);                                                 \
        const int tl_ = (i_ < nA) ? 0 : 1;                                     \
        const int cc_ = i_ - (tl_ ? nA : 0);                                   \
        const int xo_ = ((cc_ * 16 + bt2) * 64 + lane) * 8;                    \
        F.bh0 = *reinterpret_cast<const bf16x8*>(XH + xo_);                    \
        F.bh1 = *reinterpret_cast<const bf16x8*>(XH + xo_ + 512);              \
        F.bl0 = *reinterpret_cast<const bf16x8*>(XL + xo_);                    \
        F.bl1 = *reinterpret_cast<const bf16x8*>(XL + xo_ + 512);              \
        const int d_ = (tl_ ? tB64 : tA64) - cc_ * 32;                         \
        F.d0 = d_; F.tile = tl_;                                               \
        const int m0_ = (d_ > 0 ? d_ : 0) >> 4;                                \
        const int m1_ = (d_ + 16 > 0 ? d_ + 16 : 0) >> 4;                      \
        const int m2_ = (d_ + 32 > 0 ? d_ + 32 : 0) >> 4;                      \
        const int m3_ = (d_ + 48 > 0 ? d_ + 48 : 0) >> 4;                      \
        F.ah0 = *reinterpret_cast<const bf16x8*>(AH + (m0_ * 64 + lane) * 8);  \
        F.al0 = *reinterpret_cast<const bf16x8*>(AL + (m0_ * 64 + lane) * 8);  \
        F.ah1 = *reinterpret_cast<const bf16x8*>(AH + (m1_ * 64 + lane) * 8);  \
        F.al1 = *reinterpret_cast<const bf16x8*>(AL + (m1_ * 64 + lane) * 8);  \
        F.ah2 = *reinterpret_cast<const bf16x8*>(AH + (m2_ * 64 + lane) * 8);  \
        F.al2 = *reinterpret_cast<const bf16x8*>(AL + (m2_ * 64 + lane) * 8);  \
        F.ah3 = *reinterpret_cast<const bf16x8*>(AH + (m3_ * 64 + lane) * 8);  \
        F.al3 = *reinterpret_cast<const bf16x8*>(AL + (m3_ * 64 + lane) * 8);  \
    } while (0)

#define ONER(F, T, R, AHF, ALF)                                                \
        if (F.d0 + 16 * R >= 0) {                                              \
            acc[T][R][0] = MFMA(F.AHF, F.bh0, acc[T][R][0]);                   \
            acc[T][R][1] = MFMA(F.AHF, F.bh1, acc[T][R][1]);                   \
            acc[T][R][0] = MFMA(F.AHF, F.bl0, acc[T][R][0]);                   \
            acc[T][R][1] = MFMA(F.AHF, F.bl1, acc[T][R][1]);                   \
            acc[T][R][0] = MFMA(F.ALF, F.bh0, acc[T][R][0]);                   \
            acc[T][R][1] = MFMA(F.ALF, F.bh1, acc[T][R][1]);                   \
        }

#define APPLY(F) do {                                                          \
        if (F.tile == 0) {                                                     \
            ONER(F, 0, 0, ah0, al0) ONER(F, 0, 1, ah1, al1)                    \
            ONER(F, 0, 2, ah2, al2) ONER(F, 0, 3, ah3, al3)                    \
        } else {                                                               \
            ONER(F, 1, 0, ah0, al0) ONER(F, 1, 1, ah1, al1)                    \
            ONER(F, 1, 2, ah2, al2) ONER(F, 1, 3, ah3, al3)                    \
        }                                                                      \
    } while (0)

__global__ __launch_bounds__(512) void convm(const short* __restrict__ XH,
                                             const short* __restrict__ XL,
                                             const short* __restrict__ AH,
                                             const short* __restrict__ AL,
                                             const float* __restrict__ x,
                                             const float* __restrict__ Dp,
                                             float* __restrict__ out) {
    const int pr = blockIdx.x & 31;
    const int bt = blockIdx.x >> 5;
    const int tid = threadIdx.x;
    const int w = tid >> 6, lane = tid & 63;
    const int tA64 = pr * 64, tB64 = (63 - pr) * 64;
    const int nA = 2 * pr + 2;
    const int bt2 = bt * 2;

    __shared__ float lds[16 * 64 * 34];

    f32x4 acc[2][4][2];
#pragma unroll
    for (int t_ = 0; t_ < 2; ++t_)
#pragma unroll
        for (int r_ = 0; r_ < 4; ++r_)
#pragma unroll
            for (int c_ = 0; c_ < 2; ++c_) acc[t_][r_][c_] = f32x4{0.f, 0.f, 0.f, 0.f};

    Frag f0, f1;
    LOADF(f0, w);
    int idx = w;
    while (true) {
        const int n1 = idx + 8;
        const bool h1 = n1 < 130;
        if (h1) LOADF(f1, n1);
        APPLY(f0);
        if (!h1) break;
        const int n2 = n1 + 8;
        const bool h2 = n2 < 130;
        if (h2) LOADF(f0, n2);
        APPLY(f1);
        if (!h2) break;
        idx = n2;
    }

    const int lq = lane >> 4, lr = lane & 15;
#pragma unroll
    for (int t_ = 0; t_ < 2; ++t_)
#pragma unroll
        for (int r_ = 0; r_ < 4; ++r_)
#pragma unroll
            for (int c_ = 0; c_ < 2; ++c_)
#pragma unroll
                for (int e_ = 0; e_ < 4; ++e_)
                    lds[((w * 2 + t_) * 64 + (r_ * 16 + lq * 4 + e_)) * 34 +
                        (c_ * 16 + lr)] = acc[t_][r_][c_][e_];
    __syncthreads();

    const float D = Dp[0];
    const int b = tid >> 4;
    const int t4 = (tid & 15) * 4;
#pragma unroll
    for (int t_ = 0; t_ < 2; ++t_) {
        const int tbase = t_ ? tB64 : tA64;
        float s0 = 0.f, s1 = 0.f, s2 = 0.f, s3 = 0.f;
#pragma unroll
        for (int w_ = 0; w_ < 8; ++w_) {
            const float* lp = &lds[((w_ * 2 + t_) * 64 + t4) * 34 + b];
            s0 += lp[0]; s1 += lp[34]; s2 += lp[68]; s3 += lp[102];
        }
        const int g = (bt * 32 + b) * LENGTH + tbase + t4;
        const float4 xv = *reinterpret_cast<const float4*>(x + g);
        float4 o;
        o.x = 2.f * s0 + D * xv.x;
        o.y = 2.f * s1 + D * xv.y;
        o.z = 2.f * s2 + D * xv.z;
        o.w = 2.f * s3 + D * xv.w;
        if (tbase == 0 && t4 == 0) o.x -= s0;     // t==0: fac is 1, not 2
        *reinterpret_cast<float4*>(out + g) = o;
    }
}

extern "C" void kernel_launch(void* const* d_in, const int* in_sizes, int n_in,
                              void* d_out, int out_size, void* d_ws, size_t ws_size,
                              hipStream_t stream) {
    const float* x  = (const float*)d_in[0];
    const float* A  = (const float*)d_in[1];
    const float* B  = (const float*)d_in[2];
    const float* C  = (const float*)d_in[3];
    const float* Dp = (const float*)d_in[4];
    float* out = (float*)d_out;
    float* ws  = (float*)d_ws;

    float* P2    = ws + WS_P2;
    float* P4    = ws + WS_P4;
    float* P8    = ws + WS_P8;
    float* P16   = ws + WS_P16;
    float* P32   = ws + WS_P32;
    float* P64T  = ws + WS_P64T;
    float* P128T = ws + WS_P128T;
    float* Wm    = ws + WS_W;
    float* Vm    = ws + WS_V;
    short* XHs   = (short*)(ws + WS_XH);
    short* XLs   = (short*)(ws + WS_XL);
    short* AHs   = (short*)(ws + WS_AH);
    short* ALs   = (short*)(ws + WS_AL);

    fused0<<<384, 1024, 0, stream>>>(A, x, P2, XHs, XLs);
    mmsq<<<256, 1024, 0, stream>>>(P2, P4);
    mmsq<<<256, 1024, 0, stream>>>(P4, P8);
    mmsq<<<256, 1024, 0, stream>>>(P8, P16);
    mmsq<<<256, 1024, 0, stream>>>(P16, P32);
    p64w<<<260, 1024, 0, stream>>>(P32, P64T, A, C, P16, Wm);
    mmsq<<<256, 1024, 0, stream>>>(P64T, P128T);
    vgen<<<2, 1024, 0, stream>>>(P64T, P128T, B, Vm);
    kfrag<<<32, 512, 0, stream>>>(Wm, Vm, AHs, ALs);
    convm<<<256, 512, 0, stream>>>(XHs, XLs, AHs, ALs, x, Dp, out);
}